// Round 11
// baseline (4375.702 us; speedup 1.0000x reference)
//
#include <hip/hip_runtime.h>

// LSTM forward: N=64, T=512, D=1024, H=1024
// out[n][t][h], fp32. Inputs: x(N,T,D) h0(N,H) Wx(D,4H) Wh(H,4H) b(4H), all fp32.

#define NB 64
#define TT 512
#define DD 1024
#define HH 1024
#define GG 4096

using f32x4  = __attribute__((ext_vector_type(4))) float;
using bf16x8 = __attribute__((ext_vector_type(8))) __bf16;
using u16x4  = __attribute__((ext_vector_type(4))) unsigned short;

__device__ inline unsigned short f2bf(float x) {
  union { float f; unsigned u; } v; v.f = x;
  unsigned r = v.u + 0x7fffu + ((v.u >> 16) & 1u);   // RNE
  return (unsigned short)(r >> 16);
}
__device__ inline float bfu2f(unsigned short u) {
  union { unsigned u; float f; } v; v.u = ((unsigned)u) << 16; return v.f;
}
__device__ inline float sigm(float x)     { return 1.0f / (1.0f + __expf(-x)); }
__device__ inline float tanhfast(float x) { return 1.0f - 2.0f / (__expf(2.0f * x) + 1.0f); }

// ---------------------------------------------------------------------------
// Transpose + cast: in fp32 [rows][cols]  ->  out bf16 [cols][rows]
// ---------------------------------------------------------------------------
__global__ __launch_bounds__(256) void tcast(const float* __restrict__ in,
                                             unsigned short* __restrict__ out,
                                             int rows, int cols) {
  __shared__ float tile[32][33];
  const int bx = blockIdx.x * 32;
  const int by = blockIdx.y * 32;
  const int tx = threadIdx.x;
  for (int i = threadIdx.y; i < 32; i += 8)
    tile[i][tx] = in[(size_t)(by + i) * cols + bx + tx];
  __syncthreads();
  for (int i = threadIdx.y; i < 32; i += 8)
    out[(size_t)(bx + i) * rows + by + tx] = f2bf(tile[tx][i]);
}

// init: h0 -> packed (hi<<16)|(lo&~1|tag0) into buffer 0; buffer 1 = tag-1
// dummies (t=1 consumers spin until real h_1, tag 0, arrives).
__global__ __launch_bounds__(256) void init_h(const float* __restrict__ h0,
                                              unsigned* __restrict__ hp0,
                                              unsigned* __restrict__ hp1) {
  const int idx = blockIdx.x * 256 + threadIdx.x;
  const float v = h0[idx];
  const unsigned short hi = f2bf(v);
  const unsigned short lo = f2bf(v - bfu2f(hi));
  hp0[idx] = ((unsigned)hi << 16) | ((unsigned)(lo & 0xFFFEu));   // tag 0
  hp1[idx] = 1u;                                                  // tag 1 dummy
}

// ---------------------------------------------------------------------------
// Phase 1: xw[m][g] = sum_k x[m][k] * Wx[k][g] + b[g]   (stored bf16)
// ---------------------------------------------------------------------------
#define BM 128
#define BN 128
#define BK 64
#define LDP (BK + 8)

__global__ __launch_bounds__(256) void gemm_xw(const float* __restrict__ x,
                                               const unsigned short* __restrict__ WxT,
                                               const float* __restrict__ bvec,
                                               unsigned short* __restrict__ xw) {
  __shared__ unsigned short As[BM][LDP];
  __shared__ unsigned short Bs[BN][LDP];
  const int tid  = threadIdx.x;
  const int m0   = blockIdx.y * BM;
  const int g0   = blockIdx.x * BN;
  const int wave = tid >> 6, lane = tid & 63;
  const int wm = (wave & 1) * 64, wn = (wave >> 1) * 64;
  const int lr = lane & 15, lk = (lane >> 4) * 8;

  f32x4 acc[4][4] = {};

  for (int kt = 0; kt < DD; kt += BK) {
#pragma unroll
    for (int it = 0; it < 8; ++it) {
      const int row = it * 16 + (tid >> 4);
      const int c4  = (tid & 15) * 4;
      const float4 xv = *(const float4*)(x + (size_t)(m0 + row) * DD + kt + c4);
      u16x4 us; us.x = f2bf(xv.x); us.y = f2bf(xv.y); us.z = f2bf(xv.z); us.w = f2bf(xv.w);
      *(u16x4*)&As[row][c4] = us;
    }
#pragma unroll
    for (int it = 0; it < 4; ++it) {
      const int row = it * 32 + (tid >> 3);
      const int c8  = (tid & 7) * 8;
      const uint4 wv = *(const uint4*)(WxT + (size_t)(g0 + row) * DD + kt + c8);
      *(uint4*)&Bs[row][c8] = wv;
    }
    __syncthreads();
#pragma unroll
    for (int ks = 0; ks < BK / 32; ++ks) {
      const int kk = ks * 32 + lk;
      bf16x8 af[4], bfv[4];
#pragma unroll
      for (int mi = 0; mi < 4; ++mi) af[mi]  = *(const bf16x8*)&As[wm + mi * 16 + lr][kk];
#pragma unroll
      for (int ni = 0; ni < 4; ++ni) bfv[ni] = *(const bf16x8*)&Bs[wn + ni * 16 + lr][kk];
#pragma unroll
      for (int mi = 0; mi < 4; ++mi)
#pragma unroll
        for (int ni = 0; ni < 4; ++ni)
          acc[mi][ni] = __builtin_amdgcn_mfma_f32_16x16x32_bf16(af[mi], bfv[ni], acc[mi][ni], 0, 0, 0);
    }
    __syncthreads();
  }

#pragma unroll
  for (int mi = 0; mi < 4; ++mi) {
    const int row = m0 + wm + mi * 16 + ((lane >> 4) << 2);
#pragma unroll
    for (int ni = 0; ni < 4; ++ni) {
      const int col = g0 + wn + ni * 16 + lr;
      const float bb = bvec[col];
#pragma unroll
      for (int j = 0; j < 4; ++j)
        xw[(size_t)(row + j) * GG + col] = f2bf(acc[mi][ni][j] + bb);
    }
  }
}

// ---------------------------------------------------------------------------
// Phase 2: ONE persistent kernel, all 512 timesteps. NO flags, NO barrier.
// 128 blocks x 512 threads (8 waves, 1 block/CU). Block owns 16 batch-rows
// (r0 = (bid&3)*16) x 32 hidden-cols (j0 = (bid>>2)*32) x 4 gates.
// Sync = speculative DATA-AS-FLAG (parity tag in lo-LSB of each packed h
// dword), selective per-chunk retry with s_sleep backoff.
// R10 BUG FIXED (guide rule #18): the retry reload's s_waitcnt was a
// SEPARATE asm statement -> compiler hoisted the register-only tag check
// before the wait, consuming stale VGPRs. Fix: waitcnt lives INSIDE each
// reload asm block (q-outputs + waitcnt in one block => every use of q is
// data-ordered after the wait; the R7-proven pattern), plus sched_barrier(0)
// after the retry chain as a scheduling fence.
// ---------------------------------------------------------------------------
__global__ __launch_bounds__(512, 1) void lstm_seq(
    const unsigned short* __restrict__ WhT,
    const unsigned short* __restrict__ xw,
    unsigned* __restrict__ hp0, unsigned* __restrict__ hp1,
    float* __restrict__ out) {
  __shared__ unsigned short As_hi[16][1024];   // chunk-XOR swizzled
  __shared__ unsigned short As_lo[16][1024];
  __shared__ float abuf[4][16][34];

  const int tid  = threadIdx.x;
  const int bid  = blockIdx.x;
  const int grp  = bid & 3;            // r-group (independent pipeline)
  const int qid  = bid >> 2;           // 0..31 within group
  const int r0   = grp * 16;
  const int j0   = qid * 32;
  const int w    = tid >> 6;           // wave 0..7
  const int gate = w & 3;
  const int ch   = w >> 2;             // col-half 0..1
  const int lane = tid & 63;
  const int lr   = lane & 15;
  const int kslot = lane >> 4;         // 0..3
  const int sx   = lr & 7;             // read-side swizzle key
  const int srow = tid >> 5;           // staging row 0..15
  const int swr  = srow & 7;           // write-side swizzle key
  const int re   = tid >> 5, ce = tid & 31;   // epilogue element

  // ---- preload B fragments (Wh slice) into registers: 32 x bf16x8 ----
  bf16x8 rB[32];
  {
    const unsigned short* wrow =
        WhT + ((size_t)(gate * HH + j0 + ch * 16 + lr)) * HH + kslot * 8;
#pragma unroll
    for (int ks = 0; ks < 32; ++ks)
      rB[ks] = *(const bf16x8*)&wrow[ks * 32];
  }

  float creg = 0.0f;   // cell state for (r0+re, j0+ce), exclusive to this thread

  const size_t xrc = (size_t)(r0 + re) * TT * GG + j0 + ce;
  unsigned short xc0 = xw[xrc + 0 * HH];
  unsigned short xc1 = xw[xrc + 1 * HH];
  unsigned short xc2 = xw[xrc + 2 * HH];
  unsigned short xc3 = xw[xrc + 3 * HH];

  for (int t = 0; t < TT; ++t) {
    unsigned* hp = (t & 1) ? hp1 : hp0;   // read buffer (holds h_t)
    unsigned* np = (t & 1) ? hp0 : hp1;   // write buffer (gets h_{t+1})

    // ---- prefetch next step's xw FIRST (latency hides under the spin) ----
    const int tn = (t + 1 < TT) ? t + 1 : t;
    const size_t xa = xrc + (size_t)tn * GG;
    const unsigned short nx0 = xw[xa + 0 * HH];
    const unsigned short nx1 = xw[xa + 1 * HH];
    const unsigned short nx2 = xw[xa + 2 * HH];
    const unsigned short nx3 = xw[xa + 3 * HH];

    // ---- stage h rows r0..r0+15 into swizzled LDS; tag-verified loads ----
    const unsigned* hrow = hp + (size_t)(r0 + srow) * HH;
    const int c0 = 0 * 32 + (tid & 31), c1 = 1 * 32 + (tid & 31);
    const int c2 = 2 * 32 + (tid & 31), c3 = 3 * 32 + (tid & 31);
    const unsigned* p0 = hrow + c0 * 8;
    const unsigned* p1 = hrow + c1 * 8;
    const unsigned* p2 = hrow + c2 * 8;
    const unsigned* p3 = hrow + c3 * 8;
    const unsigned expect = (unsigned)((t >> 1) & 1);
    uint4 q0, q1, q2, q3, q4, q5, q6, q7;
    // speculative burst: 8 coherent dwordx4 + waitcnt in ONE asm block
    // (outputs are data-ordered after the wait -> safe use)
    asm volatile(
        "global_load_dwordx4 %0, %[a0], off sc0 sc1\n\t"
        "global_load_dwordx4 %1, %[a0], off offset:16 sc0 sc1\n\t"
        "global_load_dwordx4 %2, %[a1], off sc0 sc1\n\t"
        "global_load_dwordx4 %3, %[a1], off offset:16 sc0 sc1\n\t"
        "global_load_dwordx4 %4, %[a2], off sc0 sc1\n\t"
        "global_load_dwordx4 %5, %[a2], off offset:16 sc0 sc1\n\t"
        "global_load_dwordx4 %6, %[a3], off sc0 sc1\n\t"
        "global_load_dwordx4 %7, %[a3], off offset:16 sc0 sc1\n\t"
        "s_waitcnt vmcnt(0)"
        : "=&v"(q0), "=&v"(q1), "=&v"(q2), "=&v"(q3),
          "=&v"(q4), "=&v"(q5), "=&v"(q6), "=&v"(q7)
        : [a0] "v"(p0), [a1] "v"(p1), [a2] "v"(p2), [a3] "v"(p3)
        : "memory");

#define TAGOK(QA, QB)                                                         \
    (expect ? ((QA.x & QA.y & QA.z & QA.w & QB.x & QB.y & QB.z & QB.w) & 1u)  \
            : ((~(QA.x | QA.y | QA.z | QA.w | QB.x | QB.y | QB.z | QB.w)) & 1u))
// waitcnt INSIDE the block: q-use after this is ordered by data dependence
#define RELOAD2(QA, QB, PP)                                                   \
    asm volatile(                                                             \
        "global_load_dwordx4 %0, %[ap], off sc0 sc1\n\t"                      \
        "global_load_dwordx4 %1, %[ap], off offset:16 sc0 sc1\n\t"            \
        "s_waitcnt vmcnt(0)"                                                  \
        : "=&v"(QA), "=&v"(QB) : [ap] "v"(PP) : "memory")

    for (;;) {
      const unsigned ok0 = TAGOK(q0, q1), ok1 = TAGOK(q2, q3);
      const unsigned ok2 = TAGOK(q4, q5), ok3 = TAGOK(q6, q7);
      if (ok0 & ok1 & ok2 & ok3) break;
      __builtin_amdgcn_s_sleep(1);               // backoff: keep fabric clear
      if (!ok0) RELOAD2(q0, q1, p0);
      if (!ok1) RELOAD2(q2, q3, p1);
      if (!ok2) RELOAD2(q4, q5, p2);
      if (!ok3) RELOAD2(q6, q7, p3);
      __builtin_amdgcn_sched_barrier(0);         // rule-#18 scheduling fence
    }
#undef TAGOK
#undef RELOAD2

#define UNPACK(QA, QB, CC)                                                    \
    {                                                                         \
      const int sc = (CC) ^ swr;                                              \
      uint4 HI, LO;                                                           \
      HI.x = (QA.x >> 16) | (QA.y & 0xffff0000u);                             \
      HI.y = (QA.z >> 16) | (QA.w & 0xffff0000u);                             \
      HI.z = (QB.x >> 16) | (QB.y & 0xffff0000u);                             \
      HI.w = (QB.z >> 16) | (QB.w & 0xffff0000u);                             \
      LO.x = (QA.x & 0xffffu) | (QA.y << 16);                                 \
      LO.y = (QA.z & 0xffffu) | (QA.w << 16);                                 \
      LO.z = (QB.x & 0xffffu) | (QB.y << 16);                                 \
      LO.w = (QB.z & 0xffffu) | (QB.w << 16);                                 \
      *(uint4*)&As_hi[srow][sc * 8] = HI;                                     \
      *(uint4*)&As_lo[srow][sc * 8] = LO;                                     \
    }
    UNPACK(q0, q1, c0) UNPACK(q2, q3, c1) UNPACK(q4, q5, c2) UNPACK(q6, q7, c3)
#undef UNPACK
    __syncthreads();

    // ---- MFMA: a[16 rows][16 cols of (gate,ch)] over k=1024, hi/lo split ----
    f32x4 aHE = {}, aHO = {}, aLE = {}, aLO = {};
#pragma unroll
    for (int ks = 0; ks < 32; ks += 2) {
      const int cc0 = ((ks)     * 4 + kslot) ^ sx;
      const int cc1 = ((ks + 1) * 4 + kslot) ^ sx;
      const bf16x8 ah0 = *(const bf16x8*)&As_hi[lr][cc0 * 8];
      const bf16x8 al0 = *(const bf16x8*)&As_lo[lr][cc0 * 8];
      const bf16x8 ah1 = *(const bf16x8*)&As_hi[lr][cc1 * 8];
      const bf16x8 al1 = *(const bf16x8*)&As_lo[lr][cc1 * 8];
      aHE = __builtin_amdgcn_mfma_f32_16x16x32_bf16(ah0, rB[ks],     aHE, 0, 0, 0);
      aLE = __builtin_amdgcn_mfma_f32_16x16x32_bf16(al0, rB[ks],     aLE, 0, 0, 0);
      aHO = __builtin_amdgcn_mfma_f32_16x16x32_bf16(ah1, rB[ks + 1], aHO, 0, 0, 0);
      aLO = __builtin_amdgcn_mfma_f32_16x16x32_bf16(al1, rB[ks + 1], aLO, 0, 0, 0);
    }
    const f32x4 accv = (aHE + aHO) + (aLE + aLO);

    // ---- wave writes its 16x16 gate tile (exclusive region) ----
#pragma unroll
    for (int j = 0; j < 4; ++j)
      abuf[gate][(lane >> 4) * 4 + j][ch * 16 + lr] = accv[j];
    __syncthreads();

    // ---- gates + state update (1 element/thread) ----
    const float ai = abuf[0][re][ce] + bfu2f(xc0);
    const float af = abuf[1][re][ce] + bfu2f(xc1);
    const float ao = abuf[2][re][ce] + bfu2f(xc2);
    const float ag = abuf[3][re][ce] + bfu2f(xc3);

    const float gi = sigm(ai), gf = sigm(af), go = sigm(ao), gg = tanhfast(ag);
    creg = gf * creg + gi * gg;
    const float hn = go * tanhfast(creg);

    out[((size_t)(r0 + re) * TT + t) * HH + j0 + ce] = hn;
    const unsigned short hi = f2bf(hn);
    const unsigned short lo = f2bf(hn - bfu2f(hi));
    const unsigned tag = (unsigned)(((t + 1) >> 1) & 1);
    const unsigned pack = ((unsigned)hi << 16) | ((unsigned)(lo & 0xFFFEu) | tag);
    __hip_atomic_store(&np[(size_t)(r0 + re) * HH + j0 + ce], pack,
                       __ATOMIC_RELAXED, __HIP_MEMORY_SCOPE_AGENT);

    xc0 = nx0; xc1 = nx1; xc2 = nx2; xc3 = nx3;
    // no flags, no release barrier: next iteration's tag spin synchronizes;
    // the internal __syncthreads after staging orders reads before writes.
  }
}

// ---------------------------------------------------------------------------
extern "C" void kernel_launch(void* const* d_in, const int* in_sizes, int n_in,
                              void* d_out, int out_size, void* d_ws, size_t ws_size,
                              hipStream_t stream) {
  const float* x  = (const float*)d_in[0];
  const float* h0 = (const float*)d_in[1];
  const float* Wx = (const float*)d_in[2];
  const float* Wh = (const float*)d_in[3];
  const float* b  = (const float*)d_in[4];
  float* out = (float*)d_out;

  // workspace layout
  unsigned short* xw  = (unsigned short*)d_ws;              // 32768*4096 bf16 = 256 MB
  unsigned short* WxT = xw  + (size_t)NB * TT * GG;         // 8 MB
  unsigned short* WhT = WxT + (size_t)GG * DD;              // 8 MB
  unsigned* hp0 = (unsigned*)(WhT + (size_t)GG * HH);       // 64*1024 uints = 256 KB
  unsigned* hp1 = hp0 + (size_t)NB * HH;                    // 256 KB

  tcast<<<dim3(GG / 32, DD / 32), dim3(32, 8), 0, stream>>>(Wx, WxT, DD, GG);
  tcast<<<dim3(GG / 32, HH / 32), dim3(32, 8), 0, stream>>>(Wh, WhT, HH, GG);
  init_h<<<NB * HH / 256, 256, 0, stream>>>(h0, hp0, hp1);
  gemm_xw<<<dim3(GG / BN, NB * TT / BM), 256, 0, stream>>>(x, WxT, b, xw);

  lstm_seq<<<128, 512, 0, stream>>>(WhT, xw, hp0, hp1, out);
}

// Round 12
// 3183.527 us; speedup vs baseline: 1.3745x; 1.3745x over previous
//
#include <hip/hip_runtime.h>

// LSTM forward: N=64, T=512, D=1024, H=1024
// out[n][t][h], fp32. Inputs: x(N,T,D) h0(N,H) Wx(D,4H) Wh(H,4H) b(4H), all fp32.

#define NB 64
#define TT 512
#define DD 1024
#define HH 1024
#define GG 4096
#define FSTRIDE 32   // flag padding: 128B per flag line

using f32x4  = __attribute__((ext_vector_type(4))) float;
using bf16x8 = __attribute__((ext_vector_type(8))) __bf16;
using u16x4  = __attribute__((ext_vector_type(4))) unsigned short;

__device__ inline unsigned short f2bf(float x) {
  union { float f; unsigned u; } v; v.f = x;
  unsigned r = v.u + 0x7fffu + ((v.u >> 16) & 1u);   // RNE
  return (unsigned short)(r >> 16);
}
__device__ inline float bfu2f(unsigned short u) {
  union { unsigned u; float f; } v; v.u = ((unsigned)u) << 16; return v.f;
}
__device__ inline float sigm(float x)     { return 1.0f / (1.0f + __expf(-x)); }
__device__ inline float tanhfast(float x) { return 1.0f - 2.0f / (__expf(2.0f * x) + 1.0f); }

// async global->LDS, 16B per lane (guide: m97-proven; LDS dest must be
// wave-uniform base + lane*16, which our chunk mapping satisfies)
typedef unsigned int u32t;
__device__ inline void gl2lds16(const void* g, void* l) {
  __builtin_amdgcn_global_load_lds(
      (const __attribute__((address_space(1))) u32t*)g,
      (__attribute__((address_space(3))) u32t*)l, 16, 0, 0);
}

// ---------------------------------------------------------------------------
// Transpose + cast: in fp32 [rows][cols]  ->  out bf16 [cols][rows]
// ---------------------------------------------------------------------------
__global__ __launch_bounds__(256) void tcast(const float* __restrict__ in,
                                             unsigned short* __restrict__ out,
                                             int rows, int cols) {
  __shared__ float tile[32][33];
  const int bx = blockIdx.x * 32;
  const int by = blockIdx.y * 32;
  const int tx = threadIdx.x;
  for (int i = threadIdx.y; i < 32; i += 8)
    tile[i][tx] = in[(size_t)(by + i) * cols + bx + tx];
  __syncthreads();
  for (int i = threadIdx.y; i < 32; i += 8)
    out[(size_t)(bx + i) * rows + by + tx] = f2bf(tile[tx][i]);
}

// straight cast: x fp32 -> bf16 (same RNE as in-staging conversion)
__global__ __launch_bounds__(256) void cast_x(const float* __restrict__ in,
                                              unsigned short* __restrict__ outp) {
  const size_t i = ((size_t)blockIdx.x * 256 + threadIdx.x) * 8;
  const float4 a = *(const float4*)(in + i);
  const float4 b = *(const float4*)(in + i + 4);
  u16x4 ua, ub;
  ua.x = f2bf(a.x); ua.y = f2bf(a.y); ua.z = f2bf(a.z); ua.w = f2bf(a.w);
  ub.x = f2bf(b.x); ub.y = f2bf(b.y); ub.z = f2bf(b.z); ub.w = f2bf(b.w);
  *(u16x4*)(outp + i)     = ua;
  *(u16x4*)(outp + i + 4) = ub;
}

// init: h0 -> packed (hi<<16)|(lo&~1|tag0) into buffer 0; buffer 1 = tag-1
// dummies (t=1 consumers spin until real h_1, tag 0, arrives). Zero flags.
__global__ __launch_bounds__(256) void init_h(const float* __restrict__ h0,
                                              unsigned* __restrict__ hp0,
                                              unsigned* __restrict__ hp1,
                                              int* __restrict__ bar) {
  const int idx = blockIdx.x * 256 + threadIdx.x;
  const float v = h0[idx];
  const unsigned short hi = f2bf(v);
  const unsigned short lo = f2bf(v - bfu2f(hi));
  hp0[idx] = ((unsigned)hi << 16) | ((unsigned)(lo & 0xFFFEu));   // tag 0
  hp1[idx] = 1u;                                                  // tag 1 dummy
  if (blockIdx.x == 0)
    for (int i = threadIdx.x; i < 256 * FSTRIDE; i += 256) bar[i] = 0;
}

// ---------------------------------------------------------------------------
// Phase 1 (primary): xw = xb @ WxT^T + b, both operands bf16 [*][K] linear,
// staged via global_load_lds width-16 (m97 structure). 128x128 tile, BK=64.
// ---------------------------------------------------------------------------
__global__ __launch_bounds__(256) void gemm_xw2(const unsigned short* __restrict__ xb,
                                                const unsigned short* __restrict__ WxT,
                                                const float* __restrict__ bvec,
                                                unsigned short* __restrict__ xw) {
  __shared__ unsigned short As[128][64];
  __shared__ unsigned short Bs[128][64];
  const int tid  = threadIdx.x;
  const int g0   = blockIdx.x * 128;
  const int m0   = blockIdx.y * 128;
  const int wave = tid >> 6, lane = tid & 63;
  const int wm = (wave & 1) * 64, wn = (wave >> 1) * 64;
  const int lr = lane & 15, lk = (lane >> 4) * 8;

  f32x4 acc[4][4] = {};

  for (int kt = 0; kt < DD; kt += 64) {
    // stage: 1024 chunks of 16B each for A and B; 4+4 gload_lds per thread.
    // LDS offset = u*16 = (it*256 + wave*64)*16 + lane*16  (wave-uniform+lane)
#pragma unroll
    for (int it = 0; it < 4; ++it) {
      const int u   = it * 256 + tid;
      const int row = u >> 3;
      const int k8  = (u & 7) * 8;
      gl2lds16(xb  + (size_t)(m0 + row) * DD + kt + k8, &As[0][0] + (size_t)u * 8);
      gl2lds16(WxT + (size_t)(g0 + row) * DD + kt + k8, &Bs[0][0] + (size_t)u * 8);
    }
    __syncthreads();   // drains vmcnt -> LDS data visible
#pragma unroll
    for (int ks = 0; ks < 2; ++ks) {
      const int kk = ks * 32 + lk;
      bf16x8 af[4], bfv[4];
#pragma unroll
      for (int mi = 0; mi < 4; ++mi) af[mi]  = *(const bf16x8*)&As[wm + mi * 16 + lr][kk];
#pragma unroll
      for (int ni = 0; ni < 4; ++ni) bfv[ni] = *(const bf16x8*)&Bs[wn + ni * 16 + lr][kk];
#pragma unroll
      for (int mi = 0; mi < 4; ++mi)
#pragma unroll
        for (int ni = 0; ni < 4; ++ni)
          acc[mi][ni] = __builtin_amdgcn_mfma_f32_16x16x32_bf16(af[mi], bfv[ni], acc[mi][ni], 0, 0, 0);
    }
    __syncthreads();
  }

#pragma unroll
  for (int mi = 0; mi < 4; ++mi) {
    const int row = m0 + wm + mi * 16 + ((lane >> 4) << 2);
#pragma unroll
    for (int ni = 0; ni < 4; ++ni) {
      const int col = g0 + wn + ni * 16 + lr;
      const float bb = bvec[col];
#pragma unroll
      for (int j = 0; j < 4; ++j)
        xw[(size_t)(row + j) * GG + col] = f2bf(acc[mi][ni][j] + bb);
    }
  }
}

// ---------------------------------------------------------------------------
// Phase 1 (fallback, ws too small for xb): proven R0-R11 gemm, fp32 A with
// in-staging conversion.
// ---------------------------------------------------------------------------
#define BM 128
#define BN 128
#define BK 64
#define LDP (BK + 8)

__global__ __launch_bounds__(256) void gemm_xw(const float* __restrict__ x,
                                               const unsigned short* __restrict__ WxT,
                                               const float* __restrict__ bvec,
                                               unsigned short* __restrict__ xw) {
  __shared__ unsigned short As[BM][LDP];
  __shared__ unsigned short Bs[BN][LDP];
  const int tid  = threadIdx.x;
  const int m0   = blockIdx.y * BM;
  const int g0   = blockIdx.x * BN;
  const int wave = tid >> 6, lane = tid & 63;
  const int wm = (wave & 1) * 64, wn = (wave >> 1) * 64;
  const int lr = lane & 15, lk = (lane >> 4) * 8;

  f32x4 acc[4][4] = {};

  for (int kt = 0; kt < DD; kt += BK) {
#pragma unroll
    for (int it = 0; it < 8; ++it) {
      const int row = it * 16 + (tid >> 4);
      const int c4  = (tid & 15) * 4;
      const float4 xv = *(const float4*)(x + (size_t)(m0 + row) * DD + kt + c4);
      u16x4 us; us.x = f2bf(xv.x); us.y = f2bf(xv.y); us.z = f2bf(xv.z); us.w = f2bf(xv.w);
      *(u16x4*)&As[row][c4] = us;
    }
#pragma unroll
    for (int it = 0; it < 4; ++it) {
      const int row = it * 32 + (tid >> 3);
      const int c8  = (tid & 7) * 8;
      const uint4 wv = *(const uint4*)(WxT + (size_t)(g0 + row) * DD + kt + c8);
      *(uint4*)&Bs[row][c8] = wv;
    }
    __syncthreads();
#pragma unroll
    for (int ks = 0; ks < BK / 32; ++ks) {
      const int kk = ks * 32 + lk;
      bf16x8 af[4], bfv[4];
#pragma unroll
      for (int mi = 0; mi < 4; ++mi) af[mi]  = *(const bf16x8*)&As[wm + mi * 16 + lr][kk];
#pragma unroll
      for (int ni = 0; ni < 4; ++ni) bfv[ni] = *(const bf16x8*)&Bs[wn + ni * 16 + lr][kk];
#pragma unroll
      for (int mi = 0; mi < 4; ++mi)
#pragma unroll
        for (int ni = 0; ni < 4; ++ni)
          acc[mi][ni] = __builtin_amdgcn_mfma_f32_16x16x32_bf16(af[mi], bfv[ni], acc[mi][ni], 0, 0, 0);
    }
    __syncthreads();
  }

#pragma unroll
  for (int mi = 0; mi < 4; ++mi) {
    const int row = m0 + wm + mi * 16 + ((lane >> 4) << 2);
#pragma unroll
    for (int ni = 0; ni < 4; ++ni) {
      const int col = g0 + wn + ni * 16 + lr;
      const float bb = bvec[col];
#pragma unroll
      for (int j = 0; j < 4; ++j)
        xw[(size_t)(row + j) * GG + col] = f2bf(acc[mi][ni][j] + bb);
    }
  }
}

// ---------------------------------------------------------------------------
// Phase 2: R9 VERBATIM (proven 2.78 ms). ONE persistent kernel, 128 blocks x
// 512 threads. Flag pre-wait (32 lanes, s_sleep backoff) + tag-verified
// coherent loads; producer: tagged h stores, issue-fence, flag store.
// ---------------------------------------------------------------------------
__global__ __launch_bounds__(512, 1) void lstm_seq(
    const unsigned short* __restrict__ WhT,
    const unsigned short* __restrict__ xw,
    unsigned* __restrict__ hp0, unsigned* __restrict__ hp1,
    float* __restrict__ out, int* __restrict__ bar) {
  __shared__ unsigned short As_hi[16][1024];   // chunk-XOR swizzled
  __shared__ unsigned short As_lo[16][1024];
  __shared__ float abuf[4][16][34];

  const int tid  = threadIdx.x;
  const int bid  = blockIdx.x;
  const int grp  = bid & 3;            // r-group (independent pipeline)
  const int qid  = bid >> 2;           // 0..31 within group
  const int r0   = grp * 16;
  const int j0   = qid * 32;
  const int w    = tid >> 6;           // wave 0..7
  const int gate = w & 3;
  const int ch   = w >> 2;             // col-half 0..1
  const int lane = tid & 63;
  const int lr   = lane & 15;
  const int kslot = lane >> 4;         // 0..3
  const int sx   = lr & 7;             // read-side swizzle key
  const int srow = tid >> 5;           // staging row 0..15
  const int swr  = srow & 7;           // write-side swizzle key
  const int re   = tid >> 5, ce = tid & 31;   // epilogue element

  int* myflag = &bar[(grp * 32 + qid) * FSTRIDE];

  // ---- preload B fragments (Wh slice) into registers: 32 x bf16x8 ----
  bf16x8 rB[32];
  {
    const unsigned short* wrow =
        WhT + ((size_t)(gate * HH + j0 + ch * 16 + lr)) * HH + kslot * 8;
#pragma unroll
    for (int ks = 0; ks < 32; ++ks)
      rB[ks] = *(const bf16x8*)&wrow[ks * 32];
  }

  float creg = 0.0f;   // cell state for (r0+re, j0+ce), exclusive to this thread

  const size_t xrc = (size_t)(r0 + re) * TT * GG + j0 + ce;
  unsigned short xc0 = xw[xrc + 0 * HH];
  unsigned short xc1 = xw[xrc + 1 * HH];
  unsigned short xc2 = xw[xrc + 2 * HH];
  unsigned short xc3 = xw[xrc + 3 * HH];

  for (int t = 0; t < TT; ++t) {
    unsigned* hp = (t & 1) ? hp1 : hp0;   // read buffer (holds h_t)
    unsigned* np = (t & 1) ? hp0 : hp1;   // write buffer (gets h_{t+1})

    // ---- flag pre-wait: 32 lanes, s_sleep backoff (t=0: h0 from init) ----
    if (t > 0 && tid < 32) {
      const int* fp = &bar[(grp * 32 + tid) * FSTRIDE];
      int v = __hip_atomic_load(fp, __ATOMIC_RELAXED, __HIP_MEMORY_SCOPE_AGENT);
      while (v < t) {
        __builtin_amdgcn_s_sleep(2);
        v = __hip_atomic_load(fp, __ATOMIC_RELAXED, __HIP_MEMORY_SCOPE_AGENT);
      }
    }
    __syncthreads();

    // ---- stage h rows r0..r0+15 into swizzled LDS; tag-verify loads ----
    const unsigned* hrow = hp + (size_t)(r0 + srow) * HH;
    const int c0 = 0 * 32 + (tid & 31), c1 = 1 * 32 + (tid & 31);
    const int c2 = 2 * 32 + (tid & 31), c3 = 3 * 32 + (tid & 31);
    const unsigned* p0 = hrow + c0 * 8;
    const unsigned* p1 = hrow + c1 * 8;
    const unsigned* p2 = hrow + c2 * 8;
    const unsigned* p3 = hrow + c3 * 8;
    const unsigned expect = (unsigned)((t >> 1) & 1);
    uint4 q0, q1, q2, q3, q4, q5, q6, q7;
    for (int rtry = 0;; ++rtry) {
      asm volatile(
          "global_load_dwordx4 %0, %[a0], off sc0 sc1\n\t"
          "global_load_dwordx4 %1, %[a0], off offset:16 sc0 sc1\n\t"
          "global_load_dwordx4 %2, %[a1], off sc0 sc1\n\t"
          "global_load_dwordx4 %3, %[a1], off offset:16 sc0 sc1\n\t"
          "global_load_dwordx4 %4, %[a2], off sc0 sc1\n\t"
          "global_load_dwordx4 %5, %[a2], off offset:16 sc0 sc1\n\t"
          "global_load_dwordx4 %6, %[a3], off sc0 sc1\n\t"
          "global_load_dwordx4 %7, %[a3], off offset:16 sc0 sc1\n\t"
          "s_waitcnt vmcnt(0)"
          : "=&v"(q0), "=&v"(q1), "=&v"(q2), "=&v"(q3),
            "=&v"(q4), "=&v"(q5), "=&v"(q6), "=&v"(q7)
          : [a0] "v"(p0), [a1] "v"(p1), [a2] "v"(p2), [a3] "v"(p3)
          : "memory");
      const unsigned av = q0.x & q0.y & q0.z & q0.w & q1.x & q1.y & q1.z & q1.w &
                          q2.x & q2.y & q2.z & q2.w & q3.x & q3.y & q3.z & q3.w &
                          q4.x & q4.y & q4.z & q4.w & q5.x & q5.y & q5.z & q5.w &
                          q6.x & q6.y & q6.z & q6.w & q7.x & q7.y & q7.z & q7.w;
      const unsigned ov = q0.x | q0.y | q0.z | q0.w | q1.x | q1.y | q1.z | q1.w |
                          q2.x | q2.y | q2.z | q2.w | q3.x | q3.y | q3.z | q3.w |
                          q4.x | q4.y | q4.z | q4.w | q5.x | q5.y | q5.z | q5.w |
                          q6.x | q6.y | q6.z | q6.w | q7.x | q7.y | q7.z | q7.w;
      const unsigned chk = expect ? av : ~ov;
      if (chk & 1u) break;
      __builtin_amdgcn_s_sleep(1);   // rare: flag led a straggler store
    }

#define UNPACK(QA, QB, CC)                                                    \
    {                                                                         \
      const int sc = (CC) ^ swr;                                              \
      uint4 HI, LO;                                                           \
      HI.x = (QA.x >> 16) | (QA.y & 0xffff0000u);                             \
      HI.y = (QA.z >> 16) | (QA.w & 0xffff0000u);                             \
      HI.z = (QB.x >> 16) | (QB.y & 0xffff0000u);                             \
      HI.w = (QB.z >> 16) | (QB.w & 0xffff0000u);                             \
      LO.x = (QA.x & 0xffffu) | (QA.y << 16);                                 \
      LO.y = (QA.z & 0xffffu) | (QA.w << 16);                                 \
      LO.z = (QB.x & 0xffffu) | (QB.y << 16);                                 \
      LO.w = (QB.z & 0xffffu) | (QB.w << 16);                                 \
      *(uint4*)&As_hi[srow][sc * 8] = HI;                                     \
      *(uint4*)&As_lo[srow][sc * 8] = LO;                                     \
    }
    UNPACK(q0, q1, c0) UNPACK(q2, q3, c1) UNPACK(q4, q5, c2) UNPACK(q6, q7, c3)
#undef UNPACK
    __syncthreads();

    // ---- prefetch next step's xw under MFMA ----
    const int tn = (t + 1 < TT) ? t + 1 : t;
    const size_t xa = xrc + (size_t)tn * GG;
    const unsigned short nx0 = xw[xa + 0 * HH];
    const unsigned short nx1 = xw[xa + 1 * HH];
    const unsigned short nx2 = xw[xa + 2 * HH];
    const unsigned short nx3 = xw[xa + 3 * HH];

    // ---- MFMA: a[16 rows][16 cols of (gate,ch)] over k=1024, hi/lo split ----
    f32x4 aHE = {}, aHO = {}, aLE = {}, aLO = {};
#pragma unroll
    for (int ks = 0; ks < 32; ks += 2) {
      const int cc0 = ((ks)     * 4 + kslot) ^ sx;
      const int cc1 = ((ks + 1) * 4 + kslot) ^ sx;
      const bf16x8 ah0 = *(const bf16x8*)&As_hi[lr][cc0 * 8];
      const bf16x8 al0 = *(const bf16x8*)&As_lo[lr][cc0 * 8];
      const bf16x8 ah1 = *(const bf16x8*)&As_hi[lr][cc1 * 8];
      const bf16x8 al1 = *(const bf16x8*)&As_lo[lr][cc1 * 8];
      aHE = __builtin_amdgcn_mfma_f32_16x16x32_bf16(ah0, rB[ks],     aHE, 0, 0, 0);
      aLE = __builtin_amdgcn_mfma_f32_16x16x32_bf16(al0, rB[ks],     aLE, 0, 0, 0);
      aHO = __builtin_amdgcn_mfma_f32_16x16x32_bf16(ah1, rB[ks + 1], aHO, 0, 0, 0);
      aLO = __builtin_amdgcn_mfma_f32_16x16x32_bf16(al1, rB[ks + 1], aLO, 0, 0, 0);
    }
    const f32x4 accv = (aHE + aHO) + (aLE + aLO);

    // ---- wave writes its 16x16 gate tile (exclusive region) ----
#pragma unroll
    for (int j = 0; j < 4; ++j)
      abuf[gate][(lane >> 4) * 4 + j][ch * 16 + lr] = accv[j];
    __syncthreads();

    // ---- gates + state update (1 element/thread) ----
    const float ai = abuf[0][re][ce] + bfu2f(xc0);
    const float af = abuf[1][re][ce] + bfu2f(xc1);
    const float ao = abuf[2][re][ce] + bfu2f(xc2);
    const float ag = abuf[3][re][ce] + bfu2f(xc3);

    const float gi = sigm(ai), gf = sigm(af), go = sigm(ao), gg = tanhfast(ag);
    creg = gf * creg + gi * gg;
    const float hn = go * tanhfast(creg);

    out[((size_t)(r0 + re) * TT + t) * HH + j0 + ce] = hn;
    const unsigned short hi = f2bf(hn);
    const unsigned short lo = f2bf(hn - bfu2f(hi));
    const unsigned tag = (unsigned)(((t + 1) >> 1) & 1);
    const unsigned pack = ((unsigned)hi << 16) | ((unsigned)(lo & 0xFFFEu) | tag);
    __hip_atomic_store(&np[(size_t)(r0 + re) * HH + j0 + ce], pack,
                       __ATOMIC_RELAXED, __HIP_MEMORY_SCOPE_AGENT);

    xc0 = nx0; xc1 = nx1; xc2 = nx2; xc3 = nx3;

    // ---- release: issue-fence only (NO drain), then flag ----
    if (t + 1 < TT) {
      __syncthreads();                 // all threads' h stores issued
      if (tid == 0)
        __hip_atomic_store(myflag, t + 1, __ATOMIC_RELAXED, __HIP_MEMORY_SCOPE_AGENT);
    }
  }
}

// ---------------------------------------------------------------------------
extern "C" void kernel_launch(void* const* d_in, const int* in_sizes, int n_in,
                              void* d_out, int out_size, void* d_ws, size_t ws_size,
                              hipStream_t stream) {
  const float* x  = (const float*)d_in[0];
  const float* h0 = (const float*)d_in[1];
  const float* Wx = (const float*)d_in[2];
  const float* Wh = (const float*)d_in[3];
  const float* b  = (const float*)d_in[4];
  float* out = (float*)d_out;

  const size_t xw_elems  = (size_t)NB * TT * GG;   // 134,217,728
  const size_t xb_elems  = (size_t)NB * TT * DD;   //  33,554,432
  const size_t wT_elems  = (size_t)GG * DD;        //   4,194,304
  const size_t NH        = (size_t)NB * HH;

  // primary layout (with xb): xw | xb | WxT | WhT | hp0 | hp1 | bar
  const size_t need = (xw_elems + xb_elems + 2 * wT_elems) * 2 +
                      2 * NH * 4 + 256 * FSTRIDE * 4;
  const bool use_xb = (ws_size >= need);

  unsigned short* xw  = (unsigned short*)d_ws;
  unsigned short* xb  = xw + xw_elems;                       // only if use_xb
  unsigned short* WxT = use_xb ? (xb + xb_elems) : (xw + xw_elems);
  unsigned short* WhT = WxT + wT_elems;
  unsigned* hp0 = (unsigned*)(WhT + wT_elems);
  unsigned* hp1 = hp0 + NH;
  int* bar = (int*)(hp1 + NH);

  tcast<<<dim3(GG / 32, DD / 32), dim3(32, 8), 0, stream>>>(Wx, WxT, DD, GG);
  tcast<<<dim3(GG / 32, HH / 32), dim3(32, 8), 0, stream>>>(Wh, WhT, HH, GG);
  init_h<<<NB * HH / 256, 256, 0, stream>>>(h0, hp0, hp1, bar);

  if (use_xb) {
    cast_x<<<(int)(xb_elems / (256 * 8)), 256, 0, stream>>>(x, xb);
    gemm_xw2<<<dim3(GG / 128, NB * TT / 128), 256, 0, stream>>>(xb, WxT, b, xw);
  } else {
    gemm_xw<<<dim3(GG / BN, NB * TT / BM), 256, 0, stream>>>(x, WxT, b, xw);
  }

  lstm_seq<<<128, 512, 0, stream>>>(WhT, xw, hp0, hp1, out, bar);
}

// Round 13
// 2681.261 us; speedup vs baseline: 1.6320x; 1.1873x over previous
//
#include <hip/hip_runtime.h>

// LSTM forward: N=64, T=512, D=1024, H=1024
// out[n][t][h], fp32. Inputs: x(N,T,D) h0(N,H) Wx(D,4H) Wh(H,4H) b(4H), all fp32.

#define NB 64
#define TT 512
#define DD 1024
#define HH 1024
#define GG 4096
#define FSTRIDE 32      // flag padding: 128B per flag line
#define NCHUNK 256      // 256 chunks x 2 timesteps (t-major xw)
#define CSTRIDE 8       // chunk-counter padding (32B)

using f32x4  = __attribute__((ext_vector_type(4))) float;
using bf16x8 = __attribute__((ext_vector_type(8))) __bf16;
using u16x4  = __attribute__((ext_vector_type(4))) unsigned short;

__device__ inline unsigned short f2bf(float x) {
  union { float f; unsigned u; } v; v.f = x;
  unsigned r = v.u + 0x7fffu + ((v.u >> 16) & 1u);   // RNE
  return (unsigned short)(r >> 16);
}
__device__ inline float bfu2f(unsigned short u) {
  union { unsigned u; float f; } v; v.u = ((unsigned)u) << 16; return v.f;
}
__device__ inline float sigm(float x)     { return 1.0f / (1.0f + __expf(-x)); }
__device__ inline float tanhfast(float x) { return 1.0f - 2.0f / (__expf(2.0f * x) + 1.0f); }

// ---------------------------------------------------------------------------
// Transpose + cast: in fp32 [rows][cols]  ->  out bf16 [cols][rows]
// ---------------------------------------------------------------------------
__global__ __launch_bounds__(256) void tcast(const float* __restrict__ in,
                                             unsigned short* __restrict__ out,
                                             int rows, int cols) {
  __shared__ float tile[32][33];
  const int bx = blockIdx.x * 32;
  const int by = blockIdx.y * 32;
  const int tx = threadIdx.x;
  for (int i = threadIdx.y; i < 32; i += 8)
    tile[i][tx] = in[(size_t)(by + i) * cols + bx + tx];
  __syncthreads();
  for (int i = threadIdx.y; i < 32; i += 8)
    out[(size_t)(bx + i) * rows + by + tx] = f2bf(tile[tx][i]);
}

// init: h0 -> packed (hi<<16)|(lo&~1|tag0) buffer 0; buffer 1 = tag-1 dummy;
// zero h-flags AND xw chunk counters.
__global__ __launch_bounds__(256) void init_h(const float* __restrict__ h0,
                                              unsigned* __restrict__ hp0,
                                              unsigned* __restrict__ hp1,
                                              int* __restrict__ bar) {
  const int idx = blockIdx.x * 256 + threadIdx.x;
  const float v = h0[idx];
  const unsigned short hi = f2bf(v);
  const unsigned short lo = f2bf(v - bfu2f(hi));
  hp0[idx] = ((unsigned)hi << 16) | ((unsigned)(lo & 0xFFFEu));   // tag 0
  hp1[idx] = 1u;                                                  // tag 1 dummy
  if (blockIdx.x == 0)
    for (int i = threadIdx.x; i < 256 * FSTRIDE + NCHUNK * CSTRIDE; i += 256)
      bar[i] = 0;
}

// ---------------------------------------------------------------------------
// FUSED kernel: 256 blocks x 512 threads (1 block/CU, all resident).
//  blocks 0..127  : lstm role (R9 datapath verbatim; t-major xw reads;
//                   lane-32 chunk gate added beside the h-flag poll)
//  blocks 128..255: gemm role (xw producer, t-major; per-tile release fence
//                   + relaxed chunk counter; never waits on lstm)
// xw layout: xw[m][g], m = t*64 + r  -> M-tile (128 rows) = 2 timesteps.
// chunk c covers t in {2c, 2c+1}; done when cnt[c] == 32 (all N-tiles).
// ---------------------------------------------------------------------------
__global__ __launch_bounds__(512, 1) void lstm_fused(
    const float* __restrict__ x,
    const unsigned short* __restrict__ WxT,
    const unsigned short* __restrict__ WhT,
    const float* __restrict__ bvec,
    unsigned short* __restrict__ xw,
    unsigned* __restrict__ hp0, unsigned* __restrict__ hp1,
    float* __restrict__ out, int* __restrict__ bar) {
  __shared__ __align__(16) unsigned char smem[74240];
  const int tid = threadIdx.x;
  const int bid = blockIdx.x;
  int* cnt = bar + 256 * FSTRIDE;

  if (bid >= 128) {
    // =================== GEMM role: produce xw =============================
    unsigned short (*As)[72] = (unsigned short(*)[72])smem;           // 18432 B
    unsigned short (*Bs)[72] = (unsigned short(*)[72])(smem + 18432); // 18432 B
    const int gid  = bid - 128;
    const int wave = tid >> 6, lane = tid & 63;
    const int wm = (wave & 1) * 64, wn = (wave >> 1) * 32;
    const int lr = lane & 15, lk = (lane >> 4) * 8;

    for (int tau = gid; tau < NCHUNK * 32; tau += 128) {
      const int c  = tau >> 5;          // chunk (t-pair)
      const int n  = tau & 31;          // N-tile
      const int m0 = c * 128;
      const int g0 = n * 128;
      f32x4 acc[4][2] = {};

      for (int kt = 0; kt < DD; kt += 64) {
        // stage A: rows m0..m0+127 (permuted x rows), fp32 -> bf16
#pragma unroll
        for (int it = 0; it < 4; ++it) {
          const int rl = it * 32 + (tid >> 4);
          const int c4 = (tid & 15) * 4;
          const int m  = m0 + rl;
          const size_t xrow = (size_t)(m & 63) * TT + (m >> 6);  // (r, t)
          const float4 xv = *(const float4*)(x + xrow * DD + kt + c4);
          u16x4 us; us.x = f2bf(xv.x); us.y = f2bf(xv.y);
          us.z = f2bf(xv.z); us.w = f2bf(xv.w);
          *(u16x4*)&As[rl][c4] = us;
        }
        // stage B: WxT g-rows (bf16)
#pragma unroll
        for (int it = 0; it < 2; ++it) {
          const int rl = it * 64 + (tid >> 3);
          const int c8 = (tid & 7) * 8;
          const uint4 wv = *(const uint4*)(WxT + (size_t)(g0 + rl) * DD + kt + c8);
          *(uint4*)&Bs[rl][c8] = wv;
        }
        __syncthreads();
#pragma unroll
        for (int ks = 0; ks < 2; ++ks) {
          const int kk = ks * 32 + lk;
          bf16x8 af[4], bfv[2];
#pragma unroll
          for (int mi = 0; mi < 4; ++mi) af[mi]  = *(const bf16x8*)&As[wm + mi * 16 + lr][kk];
#pragma unroll
          for (int ni = 0; ni < 2; ++ni) bfv[ni] = *(const bf16x8*)&Bs[wn + ni * 16 + lr][kk];
#pragma unroll
          for (int mi = 0; mi < 4; ++mi)
#pragma unroll
            for (int ni = 0; ni < 2; ++ni)
              acc[mi][ni] = __builtin_amdgcn_mfma_f32_16x16x32_bf16(af[mi], bfv[ni], acc[mi][ni], 0, 0, 0);
        }
        __syncthreads();
      }

      // epilogue: bias + store (plain; flushed by the release fence below)
#pragma unroll
      for (int mi = 0; mi < 4; ++mi) {
        const int row = m0 + wm + mi * 16 + ((lane >> 4) << 2);
#pragma unroll
        for (int ni = 0; ni < 2; ++ni) {
          const int col = g0 + wn + ni * 16 + lr;
          const float bb = bvec[col];
#pragma unroll
          for (int j = 0; j < 4; ++j)
            xw[(size_t)(row + j) * GG + col] = f2bf(acc[mi][ni][j] + bb);
        }
      }
      // publish: all stores drained at barrier; tid0 flushes L2 -> L3, bumps
      __syncthreads();
      if (tid == 0) {
        __builtin_amdgcn_fence(__ATOMIC_RELEASE, "agent");
        __hip_atomic_fetch_add(&cnt[c * CSTRIDE], 1,
                               __ATOMIC_RELAXED, __HIP_MEMORY_SCOPE_AGENT);
      }
    }
    return;
  }

  // ===================== LSTM role (R9 verbatim + t-major xw) ==============
  unsigned short (*As_hi)[1024] = (unsigned short(*)[1024])smem;            // 32768
  unsigned short (*As_lo)[1024] = (unsigned short(*)[1024])(smem + 32768);  // 32768
  float (*abuf)[16][34] = (float(*)[16][34])(smem + 65536);                 //  8704

  const int grp  = bid & 3;            // r-group (independent pipeline)
  const int qid  = bid >> 2;           // 0..31 within group
  const int r0   = grp * 16;
  const int j0   = qid * 32;
  const int w    = tid >> 6;           // wave 0..7
  const int gate = w & 3;
  const int ch   = w >> 2;             // col-half 0..1
  const int lane = tid & 63;
  const int lr   = lane & 15;
  const int kslot = lane >> 4;         // 0..3
  const int sx   = lr & 7;             // read-side swizzle key
  const int srow = tid >> 5;           // staging row 0..15
  const int swr  = srow & 7;           // write-side swizzle key
  const int re   = tid >> 5, ce = tid & 31;   // epilogue element

  int* myflag = &bar[(grp * 32 + qid) * FSTRIDE];

  // ---- preload B fragments (Wh slice) into registers: 32 x bf16x8 ----
  bf16x8 rB[32];
  {
    const unsigned short* wrow =
        WhT + ((size_t)(gate * HH + j0 + ch * 16 + lr)) * HH + kslot * 8;
#pragma unroll
    for (int ks = 0; ks < 32; ++ks)
      rB[ks] = *(const bf16x8*)&wrow[ks * 32];
  }

  float creg = 0.0f;

  // t-major xw addressing: addr(u, g) = u*NB*GG + (r0+re)*GG + g*HH + j0 + ce
  const size_t xrowc = (size_t)(r0 + re) * GG + j0 + ce;
#define XWADDR(u, g) ((size_t)(u) * ((size_t)NB * GG) + xrowc + (size_t)(g) * HH)

  // ---- pre-loop: gate on chunk 0, then initial xc loads ----
  int last_c = 0;
  if (tid == 32) {
    while (__hip_atomic_load(&cnt[0], __ATOMIC_RELAXED, __HIP_MEMORY_SCOPE_AGENT) < 32)
      __builtin_amdgcn_s_sleep(2);
  }
  __syncthreads();
  unsigned short xc0 = xw[XWADDR(0, 0)];
  unsigned short xc1 = xw[XWADDR(0, 1)];
  unsigned short xc2 = xw[XWADDR(0, 2)];
  unsigned short xc3 = xw[XWADDR(0, 3)];

  for (int t = 0; t < TT; ++t) {
    unsigned* hp = (t & 1) ? hp1 : hp0;   // read buffer (holds h_t)
    unsigned* np = (t & 1) ? hp0 : hp1;   // write buffer (gets h_{t+1})

    // ---- pre-waits: h flags (lanes 0-31) + xw chunk (lane 32) ----
    if (t > 0 && tid < 32) {
      const int* fp = &bar[(grp * 32 + tid) * FSTRIDE];
      int v = __hip_atomic_load(fp, __ATOMIC_RELAXED, __HIP_MEMORY_SCOPE_AGENT);
      while (v < t) {
        __builtin_amdgcn_s_sleep(2);
        v = __hip_atomic_load(fp, __ATOMIC_RELAXED, __HIP_MEMORY_SCOPE_AGENT);
      }
    }
    if (tid == 32) {
      const int u = (t + 1 < TT) ? (t + 1) : (TT - 1);
      const int cn = u >> 1;
      if (cn > last_c) {
        while (__hip_atomic_load(&cnt[cn * CSTRIDE],
                                 __ATOMIC_RELAXED, __HIP_MEMORY_SCOPE_AGENT) < 32)
          __builtin_amdgcn_s_sleep(2);
        last_c = cn;
      }
    }
    __syncthreads();

    // ---- stage h rows r0..r0+15 into swizzled LDS; tag-verify loads ----
    const unsigned* hrow = hp + (size_t)(r0 + srow) * HH;
    const int c0 = 0 * 32 + (tid & 31), c1 = 1 * 32 + (tid & 31);
    const int c2 = 2 * 32 + (tid & 31), c3 = 3 * 32 + (tid & 31);
    const unsigned* p0 = hrow + c0 * 8;
    const unsigned* p1 = hrow + c1 * 8;
    const unsigned* p2 = hrow + c2 * 8;
    const unsigned* p3 = hrow + c3 * 8;
    const unsigned expect = (unsigned)((t >> 1) & 1);
    uint4 q0, q1, q2, q3, q4, q5, q6, q7;
    for (;;) {
      asm volatile(
          "global_load_dwordx4 %0, %[a0], off sc0 sc1\n\t"
          "global_load_dwordx4 %1, %[a0], off offset:16 sc0 sc1\n\t"
          "global_load_dwordx4 %2, %[a1], off sc0 sc1\n\t"
          "global_load_dwordx4 %3, %[a1], off offset:16 sc0 sc1\n\t"
          "global_load_dwordx4 %4, %[a2], off sc0 sc1\n\t"
          "global_load_dwordx4 %5, %[a2], off offset:16 sc0 sc1\n\t"
          "global_load_dwordx4 %6, %[a3], off sc0 sc1\n\t"
          "global_load_dwordx4 %7, %[a3], off offset:16 sc0 sc1\n\t"
          "s_waitcnt vmcnt(0)"
          : "=&v"(q0), "=&v"(q1), "=&v"(q2), "=&v"(q3),
            "=&v"(q4), "=&v"(q5), "=&v"(q6), "=&v"(q7)
          : [a0] "v"(p0), [a1] "v"(p1), [a2] "v"(p2), [a3] "v"(p3)
          : "memory");
      const unsigned av = q0.x & q0.y & q0.z & q0.w & q1.x & q1.y & q1.z & q1.w &
                          q2.x & q2.y & q2.z & q2.w & q3.x & q3.y & q3.z & q3.w &
                          q4.x & q4.y & q4.z & q4.w & q5.x & q5.y & q5.z & q5.w &
                          q6.x & q6.y & q6.z & q6.w & q7.x & q7.y & q7.z & q7.w;
      const unsigned ov = q0.x | q0.y | q0.z | q0.w | q1.x | q1.y | q1.z | q1.w |
                          q2.x | q2.y | q2.z | q2.w | q3.x | q3.y | q3.z | q3.w |
                          q4.x | q4.y | q4.z | q4.w | q5.x | q5.y | q5.z | q5.w |
                          q6.x | q6.y | q6.z | q6.w | q7.x | q7.y | q7.z | q7.w;
      const unsigned chk = expect ? av : ~ov;
      if (chk & 1u) break;
      __builtin_amdgcn_s_sleep(1);   // rare: flag led a straggler store
    }

#define UNPACK(QA, QB, CC)                                                    \
    {                                                                         \
      const int sc = (CC) ^ swr;                                              \
      uint4 HI, LO;                                                           \
      HI.x = (QA.x >> 16) | (QA.y & 0xffff0000u);                             \
      HI.y = (QA.z >> 16) | (QA.w & 0xffff0000u);                             \
      HI.z = (QB.x >> 16) | (QB.y & 0xffff0000u);                             \
      HI.w = (QB.z >> 16) | (QB.w & 0xffff0000u);                             \
      LO.x = (QA.x & 0xffffu) | (QA.y << 16);                                 \
      LO.y = (QA.z & 0xffffu) | (QA.w << 16);                                 \
      LO.z = (QB.x & 0xffffu) | (QB.y << 16);                                 \
      LO.w = (QB.z & 0xffffu) | (QB.w << 16);                                 \
      *(uint4*)&As_hi[srow][sc * 8] = HI;                                     \
      *(uint4*)&As_lo[srow][sc * 8] = LO;                                     \
    }
    UNPACK(q0, q1, c0) UNPACK(q2, q3, c1) UNPACK(q4, q5, c2) UNPACK(q6, q7, c3)
#undef UNPACK
    __syncthreads();

    // ---- prefetch next step's xw under MFMA (chunk gated at step top) ----
    const int tn = (t + 1 < TT) ? t + 1 : t;
    const unsigned short nx0 = xw[XWADDR(tn, 0)];
    const unsigned short nx1 = xw[XWADDR(tn, 1)];
    const unsigned short nx2 = xw[XWADDR(tn, 2)];
    const unsigned short nx3 = xw[XWADDR(tn, 3)];

    // ---- MFMA: a[16 rows][16 cols of (gate,ch)] over k=1024, hi/lo split ----
    f32x4 aHE = {}, aHO = {}, aLE = {}, aLO = {};
#pragma unroll
    for (int ks = 0; ks < 32; ks += 2) {
      const int cc0 = ((ks)     * 4 + kslot) ^ sx;
      const int cc1 = ((ks + 1) * 4 + kslot) ^ sx;
      const bf16x8 ah0 = *(const bf16x8*)&As_hi[lr][cc0 * 8];
      const bf16x8 al0 = *(const bf16x8*)&As_lo[lr][cc0 * 8];
      const bf16x8 ah1 = *(const bf16x8*)&As_hi[lr][cc1 * 8];
      const bf16x8 al1 = *(const bf16x8*)&As_lo[lr][cc1 * 8];
      aHE = __builtin_amdgcn_mfma_f32_16x16x32_bf16(ah0, rB[ks],     aHE, 0, 0, 0);
      aLE = __builtin_amdgcn_mfma_f32_16x16x32_bf16(al0, rB[ks],     aLE, 0, 0, 0);
      aHO = __builtin_amdgcn_mfma_f32_16x16x32_bf16(ah1, rB[ks + 1], aHO, 0, 0, 0);
      aLO = __builtin_amdgcn_mfma_f32_16x16x32_bf16(al1, rB[ks + 1], aLO, 0, 0, 0);
    }
    const f32x4 accv = (aHE + aHO) + (aLE + aLO);

    // ---- wave writes its 16x16 gate tile (exclusive region) ----
#pragma unroll
    for (int j = 0; j < 4; ++j)
      abuf[gate][(lane >> 4) * 4 + j][ch * 16 + lr] = accv[j];
    __syncthreads();

    // ---- gates + state update (1 element/thread) ----
    const float ai = abuf[0][re][ce] + bfu2f(xc0);
    const float af = abuf[1][re][ce] + bfu2f(xc1);
    const float ao = abuf[2][re][ce] + bfu2f(xc2);
    const float ag = abuf[3][re][ce] + bfu2f(xc3);

    const float gi = sigm(ai), gf = sigm(af), go = sigm(ao), gg = tanhfast(ag);
    creg = gf * creg + gi * gg;
    const float hn = go * tanhfast(creg);

    out[((size_t)(r0 + re) * TT + t) * HH + j0 + ce] = hn;
    const unsigned short hi = f2bf(hn);
    const unsigned short lo = f2bf(hn - bfu2f(hi));
    const unsigned tag = (unsigned)(((t + 1) >> 1) & 1);
    const unsigned pack = ((unsigned)hi << 16) | ((unsigned)(lo & 0xFFFEu) | tag);
    __hip_atomic_store(&np[(size_t)(r0 + re) * HH + j0 + ce], pack,
                       __ATOMIC_RELAXED, __HIP_MEMORY_SCOPE_AGENT);

    xc0 = nx0; xc1 = nx1; xc2 = nx2; xc3 = nx3;

    // ---- release: issue-fence only (NO drain), then flag ----
    if (t + 1 < TT) {
      __syncthreads();                 // all threads' h stores issued
      if (tid == 0)
        __hip_atomic_store(myflag, t + 1, __ATOMIC_RELAXED, __HIP_MEMORY_SCOPE_AGENT);
    }
  }
#undef XWADDR
}

// ---------------------------------------------------------------------------
extern "C" void kernel_launch(void* const* d_in, const int* in_sizes, int n_in,
                              void* d_out, int out_size, void* d_ws, size_t ws_size,
                              hipStream_t stream) {
  const float* x  = (const float*)d_in[0];
  const float* h0 = (const float*)d_in[1];
  const float* Wx = (const float*)d_in[2];
  const float* Wh = (const float*)d_in[3];
  const float* b  = (const float*)d_in[4];
  float* out = (float*)d_out;

  const size_t xw_elems = (size_t)NB * TT * GG;   // 134,217,728 (t-major)
  const size_t wT_elems = (size_t)GG * DD;
  const size_t NH       = (size_t)NB * HH;

  unsigned short* xw  = (unsigned short*)d_ws;               // 256 MiB
  unsigned short* WxT = xw + xw_elems;                       // 8 MiB
  unsigned short* WhT = WxT + wT_elems;                      // 8 MiB
  unsigned* hp0 = (unsigned*)(WhT + wT_elems);               // 256 KiB
  unsigned* hp1 = hp0 + NH;                                  // 256 KiB
  int* bar = (int*)(hp1 + NH);                               // flags + chunk counters

  tcast<<<dim3(GG / 32, DD / 32), dim3(32, 8), 0, stream>>>(Wx, WxT, DD, GG);
  tcast<<<dim3(GG / 32, HH / 32), dim3(32, 8), 0, stream>>>(Wh, WhT, HH, GG);
  init_h<<<NB * HH / 256, 256, 0, stream>>>(h0, hp0, hp1, bar);

  lstm_fused<<<256, 512, 0, stream>>>(x, WxT, WhT, b, xw, hp0, hp1, out, bar);
}

// Round 14
// 2675.760 us; speedup vs baseline: 1.6353x; 1.0021x over previous
//
#include <hip/hip_runtime.h>

// LSTM forward: N=64, T=512, D=1024, H=1024
// out[n][t][h], fp32. Inputs: x(N,T,D) h0(N,H) Wx(D,4H) Wh(H,4H) b(4H), all fp32.

#define NB 64
#define TT 512
#define DD 1024
#define HH 1024
#define GG 4096
#define FSTRIDE 32      // flag padding: 128B per flag line
#define NCHUNK 256      // 256 chunks x 2 timesteps (t-major xw)
#define CSTRIDE 8       // chunk-counter padding (32B)

using f32x4  = __attribute__((ext_vector_type(4))) float;
using bf16x8 = __attribute__((ext_vector_type(8))) __bf16;
using u16x4  = __attribute__((ext_vector_type(4))) unsigned short;

__device__ inline unsigned short f2bf(float x) {
  union { float f; unsigned u; } v; v.f = x;
  unsigned r = v.u + 0x7fffu + ((v.u >> 16) & 1u);   // RNE
  return (unsigned short)(r >> 16);
}
__device__ inline float bfu2f(unsigned short u) {
  union { unsigned u; float f; } v; v.u = ((unsigned)u) << 16; return v.f;
}
__device__ inline float sigm(float x)     { return 1.0f / (1.0f + __expf(-x)); }
__device__ inline float tanhfast(float x) { return 1.0f - 2.0f / (__expf(2.0f * x) + 1.0f); }

// init: h0 -> packed (hi<<16)|(lo&~1|tag0) buffer 0; buffer 1 = tag-1 dummy;
// zero h-flags, xw chunk counters, and the wT-ready counter.
__global__ __launch_bounds__(256) void init_h(const float* __restrict__ h0,
                                              unsigned* __restrict__ hp0,
                                              unsigned* __restrict__ hp1,
                                              int* __restrict__ bar) {
  const int idx = blockIdx.x * 256 + threadIdx.x;
  const float v = h0[idx];
  const unsigned short hi = f2bf(v);
  const unsigned short lo = f2bf(v - bfu2f(hi));
  hp0[idx] = ((unsigned)hi << 16) | ((unsigned)(lo & 0xFFFEu));   // tag 0
  hp1[idx] = 1u;                                                  // tag 1 dummy
  if (blockIdx.x == 0)
    for (int i = threadIdx.x; i < 256 * FSTRIDE + NCHUNK * CSTRIDE + 8; i += 256)
      bar[i] = 0;
}

// ---------------------------------------------------------------------------
// FUSED kernel: 256 blocks x 512 threads (1 block/CU, all resident).
//  blocks 128..255 (gemm role): (A) transpose a 32-row slice of WxT and WhT
//    (coalesced float4 column gather -> 16B bf16 stores), release-fence,
//    bump wT counter; (B) wait wT==128; (C) produce xw chunks (t-major,
//    per-tile release fence + chunk counter). Never waits on lstm.
//  blocks 0..127 (lstm role): wait wT==128, preload Wh fragments, then the
//    R9-verbatim recurrence with t-major xw reads, chunk gate on lane 32,
//    and HOT flag spin (no s_sleep) on lanes 0..31.
// Cache safety: consumers first touch WxT/WhT/xw lines only after the
// producer's release fence (L2->L3 flush) + counter bump; per-dispatch L1/L2
// start invalidated, so first touch fetches fresh from L3.
// ---------------------------------------------------------------------------
__global__ __launch_bounds__(512, 1) void lstm_fused(
    const float* __restrict__ x,
    const float* __restrict__ Wx,
    const float* __restrict__ Wh,
    const float* __restrict__ bvec,
    unsigned short* __restrict__ WxT,
    unsigned short* __restrict__ WhT,
    unsigned short* __restrict__ xw,
    unsigned* __restrict__ hp0, unsigned* __restrict__ hp1,
    float* __restrict__ out, int* __restrict__ bar) {
  __shared__ __align__(16) unsigned char smem[74240];
  const int tid = threadIdx.x;
  const int bid = blockIdx.x;
  int* cnt   = bar + 256 * FSTRIDE;
  int* wTcnt = cnt + NCHUNK * CSTRIDE;

  if (bid >= 128) {
    // =================== GEMM role ========================================
    const int gid = bid - 128;

    // ---- (A) transpose my 32 g-rows of WxT and WhT ----
    // thread: g-quad gq = tid&7 (4 g's), k-group ks16 = tid>>3 (16 k's)
    {
      const int g0t = gid * 32;
      const int gq  = (tid & 7) * 4;
      const int kb  = (tid >> 3) * 16;
#define TRANSP(SRC, DST)                                                      \
      {                                                                       \
        unsigned short col[4][16];                                            \
        _Pragma("unroll")                                                     \
        for (int i = 0; i < 16; ++i) {                                        \
          const float4 f4 = *(const float4*)(SRC + (size_t)(kb + i) * GG + g0t + gq); \
          col[0][i] = f2bf(f4.x); col[1][i] = f2bf(f4.y);                     \
          col[2][i] = f2bf(f4.z); col[3][i] = f2bf(f4.w);                     \
        }                                                                     \
        _Pragma("unroll")                                                     \
        for (int j = 0; j < 4; ++j) {                                         \
          *(u16x4*)(DST + (size_t)(g0t + gq + j) * DD + kb)      = *(u16x4*)&col[j][0];  \
          *(u16x4*)(DST + (size_t)(g0t + gq + j) * DD + kb + 4)  = *(u16x4*)&col[j][4];  \
          *(u16x4*)(DST + (size_t)(g0t + gq + j) * DD + kb + 8)  = *(u16x4*)&col[j][8];  \
          *(u16x4*)(DST + (size_t)(g0t + gq + j) * DD + kb + 12) = *(u16x4*)&col[j][12]; \
        }                                                                     \
      }
      TRANSP(Wx, WxT)
      TRANSP(Wh, WhT)
#undef TRANSP
    }
    __syncthreads();   // drains all stores (vmcnt) for this block
    if (tid == 0) {
      __builtin_amdgcn_fence(__ATOMIC_RELEASE, "agent");   // flush to L3
      __hip_atomic_fetch_add(wTcnt, 1, __ATOMIC_RELAXED, __HIP_MEMORY_SCOPE_AGENT);
    }
    // ---- (B) wait for all 128 transpose slices ----
    if (tid == 0) {
      while (__hip_atomic_load(wTcnt, __ATOMIC_RELAXED, __HIP_MEMORY_SCOPE_AGENT) < 128)
        __builtin_amdgcn_s_sleep(2);
    }
    __syncthreads();

    // ---- (C) produce xw chunks ----
    unsigned short (*As)[72] = (unsigned short(*)[72])smem;           // 18432 B
    unsigned short (*Bs)[72] = (unsigned short(*)[72])(smem + 18432); // 18432 B
    const int wave = tid >> 6, lane = tid & 63;
    const int wm = (wave & 1) * 64, wn = (wave >> 1) * 32;
    const int lr = lane & 15, lk = (lane >> 4) * 8;

    for (int tau = gid; tau < NCHUNK * 32; tau += 128) {
      const int c  = tau >> 5;          // chunk (t-pair)
      const int n  = tau & 31;          // N-tile
      const int m0 = c * 128;
      const int g0 = n * 128;
      f32x4 acc[4][2] = {};

      for (int kt = 0; kt < DD; kt += 64) {
#pragma unroll
        for (int it = 0; it < 4; ++it) {
          const int rl = it * 32 + (tid >> 4);
          const int c4 = (tid & 15) * 4;
          const int m  = m0 + rl;
          const size_t xrow = (size_t)(m & 63) * TT + (m >> 6);  // (r, t)
          const float4 xv = *(const float4*)(x + xrow * DD + kt + c4);
          u16x4 us; us.x = f2bf(xv.x); us.y = f2bf(xv.y);
          us.z = f2bf(xv.z); us.w = f2bf(xv.w);
          *(u16x4*)&As[rl][c4] = us;
        }
#pragma unroll
        for (int it = 0; it < 2; ++it) {
          const int rl = it * 64 + (tid >> 3);
          const int c8 = (tid & 7) * 8;
          const uint4 wv = *(const uint4*)(WxT + (size_t)(g0 + rl) * DD + kt + c8);
          *(uint4*)&Bs[rl][c8] = wv;
        }
        __syncthreads();
#pragma unroll
        for (int ks = 0; ks < 2; ++ks) {
          const int kk = ks * 32 + lk;
          bf16x8 af[4], bfv[2];
#pragma unroll
          for (int mi = 0; mi < 4; ++mi) af[mi]  = *(const bf16x8*)&As[wm + mi * 16 + lr][kk];
#pragma unroll
          for (int ni = 0; ni < 2; ++ni) bfv[ni] = *(const bf16x8*)&Bs[wn + ni * 16 + lr][kk];
#pragma unroll
          for (int mi = 0; mi < 4; ++mi)
#pragma unroll
            for (int ni = 0; ni < 2; ++ni)
              acc[mi][ni] = __builtin_amdgcn_mfma_f32_16x16x32_bf16(af[mi], bfv[ni], acc[mi][ni], 0, 0, 0);
        }
        __syncthreads();
      }

#pragma unroll
      for (int mi = 0; mi < 4; ++mi) {
        const int row = m0 + wm + mi * 16 + ((lane >> 4) << 2);
#pragma unroll
        for (int ni = 0; ni < 2; ++ni) {
          const int col = g0 + wn + ni * 16 + lr;
          const float bb = bvec[col];
#pragma unroll
          for (int j = 0; j < 4; ++j)
            xw[(size_t)(row + j) * GG + col] = f2bf(acc[mi][ni][j] + bb);
        }
      }
      __syncthreads();
      if (tid == 0) {
        __builtin_amdgcn_fence(__ATOMIC_RELEASE, "agent");
        __hip_atomic_fetch_add(&cnt[c * CSTRIDE], 1,
                               __ATOMIC_RELAXED, __HIP_MEMORY_SCOPE_AGENT);
      }
    }
    return;
  }

  // ===================== LSTM role =========================================
  unsigned short (*As_hi)[1024] = (unsigned short(*)[1024])smem;            // 32768
  unsigned short (*As_lo)[1024] = (unsigned short(*)[1024])(smem + 32768);  // 32768
  float (*abuf)[16][34] = (float(*)[16][34])(smem + 65536);                 //  8704

  const int grp  = bid & 3;            // r-group (independent pipeline)
  const int qid  = bid >> 2;           // 0..31 within group
  const int r0   = grp * 16;
  const int j0   = qid * 32;
  const int w    = tid >> 6;           // wave 0..7
  const int gate = w & 3;
  const int ch   = w >> 2;             // col-half 0..1
  const int lane = tid & 63;
  const int lr   = lane & 15;
  const int kslot = lane >> 4;         // 0..3
  const int sx   = lr & 7;             // read-side swizzle key
  const int srow = tid >> 5;           // staging row 0..15
  const int swr  = srow & 7;           // write-side swizzle key
  const int re   = tid >> 5, ce = tid & 31;   // epilogue element

  int* myflag = &bar[(grp * 32 + qid) * FSTRIDE];

  // ---- gate on WhT ready, then preload B fragments ----
  if (tid == 0) {
    while (__hip_atomic_load(wTcnt, __ATOMIC_RELAXED, __HIP_MEMORY_SCOPE_AGENT) < 128)
      __builtin_amdgcn_s_sleep(2);
  }
  __syncthreads();

  bf16x8 rB[32];
  {
    const unsigned short* wrow =
        WhT + ((size_t)(gate * HH + j0 + ch * 16 + lr)) * HH + kslot * 8;
#pragma unroll
    for (int ks = 0; ks < 32; ++ks)
      rB[ks] = *(const bf16x8*)&wrow[ks * 32];
  }

  float creg = 0.0f;

  const size_t xrowc = (size_t)(r0 + re) * GG + j0 + ce;
#define XWADDR(u, g) ((size_t)(u) * ((size_t)NB * GG) + xrowc + (size_t)(g) * HH)

  // ---- pre-loop: gate on chunk 0, then initial xc loads ----
  int last_c = 0;
  if (tid == 32) {
    while (__hip_atomic_load(&cnt[0], __ATOMIC_RELAXED, __HIP_MEMORY_SCOPE_AGENT) < 32)
      __builtin_amdgcn_s_sleep(2);
  }
  __syncthreads();
  unsigned short xc0 = xw[XWADDR(0, 0)];
  unsigned short xc1 = xw[XWADDR(0, 1)];
  unsigned short xc2 = xw[XWADDR(0, 2)];
  unsigned short xc3 = xw[XWADDR(0, 3)];

  for (int t = 0; t < TT; ++t) {
    unsigned* hp = (t & 1) ? hp1 : hp0;   // read buffer (holds h_t)
    unsigned* np = (t & 1) ? hp0 : hp1;   // write buffer (gets h_{t+1})

    // ---- pre-waits: h flags (lanes 0-31, HOT spin) + xw chunk (lane 32) ----
    if (t > 0 && tid < 32) {
      const int* fp = &bar[(grp * 32 + tid) * FSTRIDE];
      while (__hip_atomic_load(fp, __ATOMIC_RELAXED, __HIP_MEMORY_SCOPE_AGENT) < t) {}
    }
    if (tid == 32) {
      const int u = (t + 1 < TT) ? (t + 1) : (TT - 1);
      const int cn = u >> 1;
      if (cn > last_c) {
        while (__hip_atomic_load(&cnt[cn * CSTRIDE],
                                 __ATOMIC_RELAXED, __HIP_MEMORY_SCOPE_AGENT) < 32)
          __builtin_amdgcn_s_sleep(2);
        last_c = cn;
      }
    }
    __syncthreads();

    // ---- stage h rows r0..r0+15 into swizzled LDS; tag-verify loads ----
    const unsigned* hrow = hp + (size_t)(r0 + srow) * HH;
    const int c0 = 0 * 32 + (tid & 31), c1 = 1 * 32 + (tid & 31);
    const int c2 = 2 * 32 + (tid & 31), c3 = 3 * 32 + (tid & 31);
    const unsigned* p0 = hrow + c0 * 8;
    const unsigned* p1 = hrow + c1 * 8;
    const unsigned* p2 = hrow + c2 * 8;
    const unsigned* p3 = hrow + c3 * 8;
    const unsigned expect = (unsigned)((t >> 1) & 1);
    uint4 q0, q1, q2, q3, q4, q5, q6, q7;
    for (;;) {
      asm volatile(
          "global_load_dwordx4 %0, %[a0], off sc0 sc1\n\t"
          "global_load_dwordx4 %1, %[a0], off offset:16 sc0 sc1\n\t"
          "global_load_dwordx4 %2, %[a1], off sc0 sc1\n\t"
          "global_load_dwordx4 %3, %[a1], off offset:16 sc0 sc1\n\t"
          "global_load_dwordx4 %4, %[a2], off sc0 sc1\n\t"
          "global_load_dwordx4 %5, %[a2], off offset:16 sc0 sc1\n\t"
          "global_load_dwordx4 %6, %[a3], off sc0 sc1\n\t"
          "global_load_dwordx4 %7, %[a3], off offset:16 sc0 sc1\n\t"
          "s_waitcnt vmcnt(0)"
          : "=&v"(q0), "=&v"(q1), "=&v"(q2), "=&v"(q3),
            "=&v"(q4), "=&v"(q5), "=&v"(q6), "=&v"(q7)
          : [a0] "v"(p0), [a1] "v"(p1), [a2] "v"(p2), [a3] "v"(p3)
          : "memory");
      const unsigned av = q0.x & q0.y & q0.z & q0.w & q1.x & q1.y & q1.z & q1.w &
                          q2.x & q2.y & q2.z & q2.w & q3.x & q3.y & q3.z & q3.w &
                          q4.x & q4.y & q4.z & q4.w & q5.x & q5.y & q5.z & q5.w &
                          q6.x & q6.y & q6.z & q6.w & q7.x & q7.y & q7.z & q7.w;
      const unsigned ov = q0.x | q0.y | q0.z | q0.w | q1.x | q1.y | q1.z | q1.w |
                          q2.x | q2.y | q2.z | q2.w | q3.x | q3.y | q3.z | q3.w |
                          q4.x | q4.y | q4.z | q4.w | q5.x | q5.y | q5.z | q5.w |
                          q6.x | q6.y | q6.z | q6.w | q7.x | q7.y | q7.z | q7.w;
      const unsigned chk = expect ? av : ~ov;
      if (chk & 1u) break;
      __builtin_amdgcn_s_sleep(1);   // rare: flag led a straggler store
    }

#define UNPACK(QA, QB, CC)                                                    \
    {                                                                         \
      const int sc = (CC) ^ swr;                                              \
      uint4 HI, LO;                                                           \
      HI.x = (QA.x >> 16) | (QA.y & 0xffff0000u);                             \
      HI.y = (QA.z >> 16) | (QA.w & 0xffff0000u);                             \
      HI.z = (QB.x >> 16) | (QB.y & 0xffff0000u);                             \
      HI.w = (QB.z >> 16) | (QB.w & 0xffff0000u);                             \
      LO.x = (QA.x & 0xffffu) | (QA.y << 16);                                 \
      LO.y = (QA.z & 0xffffu) | (QA.w << 16);                                 \
      LO.z = (QB.x & 0xffffu) | (QB.y << 16);                                 \
      LO.w = (QB.z & 0xffffu) | (QB.w << 16);                                 \
      *(uint4*)&As_hi[srow][sc * 8] = HI;                                     \
      *(uint4*)&As_lo[srow][sc * 8] = LO;                                     \
    }
    UNPACK(q0, q1, c0) UNPACK(q2, q3, c1) UNPACK(q4, q5, c2) UNPACK(q6, q7, c3)
#undef UNPACK
    __syncthreads();

    // ---- prefetch next step's xw under MFMA (chunk gated at step top) ----
    const int tn = (t + 1 < TT) ? t + 1 : t;
    const unsigned short nx0 = xw[XWADDR(tn, 0)];
    const unsigned short nx1 = xw[XWADDR(tn, 1)];
    const unsigned short nx2 = xw[XWADDR(tn, 2)];
    const unsigned short nx3 = xw[XWADDR(tn, 3)];

    // ---- MFMA: a[16 rows][16 cols of (gate,ch)] over k=1024, hi/lo split ----
    f32x4 aHE = {}, aHO = {}, aLE = {}, aLO = {};
#pragma unroll
    for (int ks = 0; ks < 32; ks += 2) {
      const int cc0 = ((ks)     * 4 + kslot) ^ sx;
      const int cc1 = ((ks + 1) * 4 + kslot) ^ sx;
      const bf16x8 ah0 = *(const bf16x8*)&As_hi[lr][cc0 * 8];
      const bf16x8 al0 = *(const bf16x8*)&As_lo[lr][cc0 * 8];
      const bf16x8 ah1 = *(const bf16x8*)&As_hi[lr][cc1 * 8];
      const bf16x8 al1 = *(const bf16x8*)&As_lo[lr][cc1 * 8];
      aHE = __builtin_amdgcn_mfma_f32_16x16x32_bf16(ah0, rB[ks],     aHE, 0, 0, 0);
      aLE = __builtin_amdgcn_mfma_f32_16x16x32_bf16(al0, rB[ks],     aLE, 0, 0, 0);
      aHO = __builtin_amdgcn_mfma_f32_16x16x32_bf16(ah1, rB[ks + 1], aHO, 0, 0, 0);
      aLO = __builtin_amdgcn_mfma_f32_16x16x32_bf16(al1, rB[ks + 1], aLO, 0, 0, 0);
    }
    const f32x4 accv = (aHE + aHO) + (aLE + aLO);

    // ---- wave writes its 16x16 gate tile (exclusive region) ----
#pragma unroll
    for (int j = 0; j < 4; ++j)
      abuf[gate][(lane >> 4) * 4 + j][ch * 16 + lr] = accv[j];
    __syncthreads();

    // ---- gates + state update (1 element/thread) ----
    const float ai = abuf[0][re][ce] + bfu2f(xc0);
    const float af = abuf[1][re][ce] + bfu2f(xc1);
    const float ao = abuf[2][re][ce] + bfu2f(xc2);
    const float ag = abuf[3][re][ce] + bfu2f(xc3);

    const float gi = sigm(ai), gf = sigm(af), go = sigm(ao), gg = tanhfast(ag);
    creg = gf * creg + gi * gg;
    const float hn = go * tanhfast(creg);

    out[((size_t)(r0 + re) * TT + t) * HH + j0 + ce] = hn;
    const unsigned short hi = f2bf(hn);
    const unsigned short lo = f2bf(hn - bfu2f(hi));
    const unsigned tag = (unsigned)(((t + 1) >> 1) & 1);
    const unsigned pack = ((unsigned)hi << 16) | ((unsigned)(lo & 0xFFFEu) | tag);
    __hip_atomic_store(&np[(size_t)(r0 + re) * HH + j0 + ce], pack,
                       __ATOMIC_RELAXED, __HIP_MEMORY_SCOPE_AGENT);

    xc0 = nx0; xc1 = nx1; xc2 = nx2; xc3 = nx3;

    // ---- release: issue-fence only (NO drain), then flag ----
    if (t + 1 < TT) {
      __syncthreads();                 // all threads' h stores issued
      if (tid == 0)
        __hip_atomic_store(myflag, t + 1, __ATOMIC_RELAXED, __HIP_MEMORY_SCOPE_AGENT);
    }
  }
#undef XWADDR
}

// ---------------------------------------------------------------------------
extern "C" void kernel_launch(void* const* d_in, const int* in_sizes, int n_in,
                              void* d_out, int out_size, void* d_ws, size_t ws_size,
                              hipStream_t stream) {
  const float* x  = (const float*)d_in[0];
  const float* h0 = (const float*)d_in[1];
  const float* Wx = (const float*)d_in[2];
  const float* Wh = (const float*)d_in[3];
  const float* b  = (const float*)d_in[4];
  float* out = (float*)d_out;

  const size_t xw_elems = (size_t)NB * TT * GG;   // 134,217,728 (t-major)
  const size_t wT_elems = (size_t)GG * DD;
  const size_t NH       = (size_t)NB * HH;

  unsigned short* xw  = (unsigned short*)d_ws;               // 256 MiB
  unsigned short* WxT = xw + xw_elems;                       // 8 MiB
  unsigned short* WhT = WxT + wT_elems;                      // 8 MiB
  unsigned* hp0 = (unsigned*)(WhT + wT_elems);               // 256 KiB
  unsigned* hp1 = hp0 + NH;                                  // 256 KiB
  int* bar = (int*)(hp1 + NH);                               // flags + counters

  init_h<<<NB * HH / 256, 256, 0, stream>>>(h0, hp0, hp1, bar);
  lstm_fused<<<256, 512, 0, stream>>>(x, Wx, Wh, b, WxT, WhT, xw,
                                      hp0, hp1, out, bar);
}